// Round 6
// baseline (1343.810 us; speedup 1.0000x reference)
//
#include <hip/hip_runtime.h>

#define TPB 256

// Decision-critical math (H1, hidden, y, softmax) is f64 with one fixed,
// canonical summation structure everywhere -> equal count-triples give
// bit-identical scores, so np first-index tie-breaks are reproduced by
// strict-> comparisons in index order. (Validated in R2/R3/R5.)
// W2/cnt stored as f64 in LDS: f32->f64 widening is exact, so results are
// bit-identical to R5 while eliminating per-use v_cvt_f64_f32.
//
// Affected set of one fill = 9 row cells + 9 col cells + 4 box cells
// outside the filled row/col = 22 slots.

__device__ __forceinline__ int affected_cell(int slot, int fr, int fc) {
    if (slot < 9)  return fr * 9 + slot;            // row cells
    if (slot < 18) return (slot - 9) * 9 + fc;      // col cells
    int r0 = (fr / 3) * 3, c0 = (fc / 3) * 3;       // box cells off-row/off-col
    int dr = fr - r0, dc = fc - c0;
    int rA = r0 + (dr == 0 ? 1 : 0), rB = r0 + (dr == 2 ? 1 : 2);
    int cA = c0 + (dc == 0 ? 1 : 0), cB = c0 + (dc == 2 ? 1 : 2);
    int k = slot - 18;
    return ((k < 2) ? rA : rB) * 9 + ((k & 1) ? cB : cA);
}

// F: partial y over j-chunk q (12 j's, last chunk 4). 22 slots x 9 chunks.
__device__ __forceinline__ void do_F(int slot, int q, int cell,
    const double* __restrict__ H1, const double* __restrict__ W2Td,
    double* __restrict__ pbuf)
{
    int r = cell / 9, c = cell - 9 * r;
    int bx = (r / 3) * 3 + c / 3;
    const double* Hr = H1 + r * 101;
    const double* Hc = H1 + (9 + c) * 101;
    const double* Hb = H1 + (18 + bx) * 101;
    double acc[9];
#pragma unroll
    for (int v = 0; v < 9; v++) acc[v] = 0.0;
    const int j0 = q * 12;
#pragma unroll
    for (int jj = 0; jj < 12; jj++) {
        int j = j0 + jj;
        if (j < 100) {
            double h = Hr[j] + Hc[j] + Hb[j];
            h = h > 0.0 ? h : 0.0;
            const double* w = W2Td + j * 9;
#pragma unroll
            for (int v = 0; v < 9; v++) acc[v] = fma(h, w[v], acc[v]);
        }
    }
    double* pb = pbuf + (slot * 9 + q) * 9;
#pragma unroll
    for (int v = 0; v < 9; v++) pb[v] = acc[v];
}

// Wave-synchronous combine+softmax: a slot's 9 v-lanes live in ONE wave
// (lockstep, per-wave LDS ordering); wave_barrier fences the compiler.
__device__ __forceinline__ void do_C(int slot, int v, int cell,
    const double* __restrict__ pbuf, double* __restrict__ ybuf,
    double* __restrict__ pexp, float* __restrict__ outp,
    double* __restrict__ score_l, int* __restrict__ pos_l)
{
    double y = 0.0;
#pragma unroll
    for (int q = 0; q < 9; q++) y += pbuf[(slot * 9 + q) * 9 + v];
    ybuf[slot * 9 + v] = y;
    __builtin_amdgcn_wave_barrier();
    double m = ybuf[slot * 9 + 0];
#pragma unroll
    for (int v2 = 1; v2 < 9; v2++) m = fmax(m, ybuf[slot * 9 + v2]);
    pexp[slot * 9 + v] = exp(y - m);
    __builtin_amdgcn_wave_barrier();
    if (v == 0) {
        double sum = 0.0;
#pragma unroll
        for (int v2 = 0; v2 < 9; v2++) sum += pexp[slot * 9 + v2];
        double inv = 1.0 / sum;
        double best = -1.0; int bv = 0;
#pragma unroll
        for (int v2 = 0; v2 < 9; v2++) {
            double pr = pexp[slot * 9 + v2] * inv;
            outp[cell * 9 + v2] = (float)pr;
            if (pr > best) { best = pr; bv = v2; }  // strict > : first-index tie-break
        }
        score_l[cell] = best;
        pos_l[cell] = bv;
    }
}

__global__ __launch_bounds__(TPB, 4) void sudoku_kernel(
    const float* __restrict__ x_in,
    const float* __restrict__ W1,
    const float* __restrict__ W2,
    float* __restrict__ out,
    int nb)
{
    const int b = blockIdx.x;
    const int t = threadIdx.x;

    __shared__ float  xs[729];
    __shared__ double W2Td[100 * 9];   // W2Td[j*9+v] = (double)W2[v*100+j]
    __shared__ double cnt[27 * 12];    // exact small ints (f64: no cvt in H)
    __shared__ double H1[27 * 101];
    __shared__ double pbuf[22 * 9 * 9];  // [slot][q][v]
    __shared__ double ybuf[22 * 9];
    __shared__ double pexp[22 * 9];
    __shared__ double score_l[81];     // -1 = filled
    __shared__ int    pos_l[81];
    __shared__ int    bc_cell;

    float* outp = out + (size_t)b * 729;
    const float* xb = x_in + (size_t)b * 729;
    for (int i = t; i < 729; i += TPB) { float v = xb[i]; xs[i] = v; outp[i] = v; }
    for (int i = t; i < 900; i += TPB) { int v = i / 100, j = i - 100 * v; W2Td[j * 9 + v] = (double)W2[i]; }
    __syncthreads();

    // empty flags + initial counts
    if (t < 81) {
        float s = 0.f;
#pragma unroll
        for (int v = 0; v < 9; v++) s += xs[t * 9 + v];
        score_l[t] = (s == 0.f) ? 0.0 : -1.0;
        pos_l[t] = 0;
    }
    for (int o = t; o < 243; o += TPB) {
        int g = o / 9, v = o - 9 * g;
        float s = 0.f;
        if (g < 9) {
            int base = g * 9;
#pragma unroll
            for (int k = 0; k < 9; k++) s += xs[(base + k) * 9 + v];
        } else if (g < 18) {
            int c = g - 9;
#pragma unroll
            for (int k = 0; k < 9; k++) s += xs[(c + 9 * k) * 9 + v];
        } else {
            int bx = g - 18;
            int base = (bx / 3) * 27 + (bx % 3) * 3;
#pragma unroll
            for (int k = 0; k < 9; k++) s += xs[(base + (k / 3) * 9 + (k % 3)) * 9 + v];
        }
        cnt[g * 12 + v] = (double)s;
    }
    __syncthreads();

    // full H1 init (canonical v-order; W1 from global, L1-hot)
    for (int o = t; o < 2700; o += TPB) {
        int g = o / 100, j = o - 100 * g;
        int type = (g >= 18) ? 2 : (g >= 9 ? 1 : 0);
        const float* w = W1 + j * 27 + type * 9;
        const double* cc = cnt + g * 12;
        double s = 0.0;
#pragma unroll
        for (int v = 0; v < 9; v++) s = fma((double)w[v], cc[v], s);
        H1[g * 101 + j] = s;
    }
    int myflag = (t < 81) ? (score_l[t] == 0.0) : 0;
    int ne = __syncthreads_count(myflag);

    // initial probs/scores for all empty cells, chunks of 22
    for (int c0 = 0; c0 < 81; c0 += 22) {
        if (t < 198) {
            int slot = t % 22, q = t / 22;
            int cell = c0 + slot;
            if (cell < 81 && score_l[cell] >= 0.0)
                do_F(slot, q, cell, H1, W2Td, pbuf);
        }
        __syncthreads();
        {
            int w = t >> 6, l = t & 63;
            if (l < 63) {
                int sw = l / 9, v = l - 9 * sw;
                int slot = w * 7 + sw;
                int cell = c0 + slot;
                if (slot < 22 && cell < 81 && score_l[cell] >= 0.0)
                    do_C(slot, v, cell, pbuf, ybuf, pexp, outp, score_l, pos_l);
            }
        }
        __syncthreads();
    }

    // main loop: one fill per iteration
    for (int step = 0; step < ne; ++step) {
        // R+A fused on wave 0: butterfly argmax (all lanes get winner),
        // lane 0 applies fill + count updates.
        if (t < 64) {
            double s = score_l[t]; int idx = t;
            if (t < 17) {
                double s2 = score_l[64 + t];
                if (s2 > s) { s = s2; idx = 64 + t; }   // tie keeps lower idx
            }
#pragma unroll
            for (int off = 1; off < 64; off <<= 1) {
                double s2 = __shfl_xor(s, off);
                int    i2 = __shfl_xor(idx, off);
                if (s2 > s || (s2 == s && i2 < idx)) { s = s2; idx = i2; }
            }
            if (t == 0) {
                int cell = idx, bv = pos_l[cell];
                bc_cell = cell;
                xs[cell * 9 + bv] = 1.0f;
                score_l[cell] = -1.0;
                int r = cell / 9, c = cell - 9 * r;
                int bx = (r / 3) * 3 + c / 3;
                cnt[r * 12 + bv] += 1.0;
                cnt[(9 + c) * 12 + bv] += 1.0;
                cnt[(18 + bx) * 12 + bv] += 1.0;
            }
        }
        __syncthreads();
        const int fcell = bc_cell;
        const int fr = fcell / 9, fc = fcell - 9 * fr;
        const int fbx = (fr / 3) * 3 + fc / 3;

        // H: fresh H1 for the 3 affected groups (canonical v-order)
        for (int o = t; o < 300; o += TPB) {
            int gi = o / 100, j = o - 100 * gi;
            int g = (gi == 0) ? fr : (gi == 1) ? (9 + fc) : (18 + fbx);
            const float* w = W1 + j * 27 + gi * 9;
            const double* cc = cnt + g * 12;
            double s = 0.0;
#pragma unroll
            for (int v = 0; v < 9; v++) s = fma((double)w[v], cc[v], s);
            H1[g * 101 + j] = s;
        }
        __syncthreads();

        // F: partial y for affected, still-empty cells (198 thr, 12 j each)
        if (t < 198) {
            int slot = t % 22, q = t / 22;
            int cell = affected_cell(slot, fr, fc);
            if (score_l[cell] >= 0.0)
                do_F(slot, q, cell, H1, W2Td, pbuf);
        }
        __syncthreads();

        // C: combine + parallel softmax + cache/update (wave-sync, 4 waves x 7 slots)
        {
            int w = t >> 6, l = t & 63;
            if (l < 63) {
                int sw = l / 9, v = l - 9 * sw;
                int slot = w * 7 + sw;
                if (slot < 22) {
                    int cell = affected_cell(slot, fr, fc);
                    if (score_l[cell] >= 0.0)
                        do_C(slot, v, cell, pbuf, ybuf, pexp, outp, score_l, pos_l);
                }
            }
        }
        __syncthreads();
    }

    float* outx = out + (size_t)nb * 729 + (size_t)b * 729;
    for (int i = t; i < 729; i += TPB) outx[i] = xs[i];
}

extern "C" void kernel_launch(void* const* d_in, const int* in_sizes, int n_in,
                              void* d_out, int out_size, void* d_ws, size_t ws_size,
                              hipStream_t stream) {
    const float* x  = (const float*)d_in[0];
    const float* W1 = (const float*)d_in[1];
    const float* W2 = (const float*)d_in[2];
    int nb = in_sizes[0] / 729;
    (void)n_in; (void)out_size; (void)d_ws; (void)ws_size;
    sudoku_kernel<<<nb, TPB, 0, stream>>>(x, W1, W2, (float*)d_out, nb);
}

// Round 7
// 1337.781 us; speedup vs baseline: 1.0045x; 1.0045x over previous
//
#include <hip/hip_runtime.h>

#define TPB 256

// Decision-critical math (H1, hidden, y, softmax) is f64 with one fixed,
// canonical summation structure everywhere -> equal count-triples give
// bit-identical scores, so np first-index tie-breaks are reproduced by
// strict-> comparisons in index order. (Validated R2/R3/R5/R6.)
// H applies the +1 count update as an EXACT inline correction
// (cv = cnt + 1.0 on small integers is exact), so the result is bit-identical
// to recomputing from updated counts; LDS state writes are deferred one phase.
//
// Affected set of one fill = 9 row + 9 col + 4 off-row/off-col box = 22 slots
// (the filled cell appears twice in row/col lists; skipped via cell != fcell).

__device__ __forceinline__ int affected_cell(int slot, int fr, int fc) {
    if (slot < 9)  return fr * 9 + slot;            // row cells
    if (slot < 18) return (slot - 9) * 9 + fc;      // col cells
    int r0 = (fr / 3) * 3, c0 = (fc / 3) * 3;       // box cells off-row/off-col
    int dr = fr - r0, dc = fc - c0;
    int rA = r0 + (dr == 0 ? 1 : 0), rB = r0 + (dr == 2 ? 1 : 2);
    int cA = c0 + (dc == 0 ? 1 : 0), cB = c0 + (dc == 2 ? 1 : 2);
    int k = slot - 18;
    return ((k < 2) ? rA : rB) * 9 + ((k & 1) ? cB : cA);
}

// Fused F+C, fully wave-local: a slot's 9 chunk-lanes are contiguous in one
// wave; pbuf/ybuf traffic is ordered by per-wave LDS FIFO + wave_barrier
// compiler fences (R5/R6-validated idiom). qv doubles as j-chunk id and v.
__device__ __forceinline__ void do_FC(int slot, int qv, int cell,
    const double* __restrict__ H1, const double* __restrict__ W2Td,
    double* __restrict__ pbuf, double* __restrict__ ybuf,
    float* __restrict__ outp, double* __restrict__ score_l, int* __restrict__ pos_l)
{
    int r = cell / 9, c = cell - 9 * r;
    int bx = (r / 3) * 3 + c / 3;
    const double* Hr = H1 + r * 101;
    const double* Hc = H1 + (9 + c) * 101;
    const double* Hb = H1 + (18 + bx) * 101;
    double acc[9];
#pragma unroll
    for (int v = 0; v < 9; v++) acc[v] = 0.0;
    const int j0 = qv * 12;
#pragma unroll
    for (int jj = 0; jj < 12; jj++) {
        int j = j0 + jj;
        if (j < 100) {
            double h = Hr[j] + Hc[j] + Hb[j];
            h = h > 0.0 ? h : 0.0;
            const double* w = W2Td + j * 9;
#pragma unroll
            for (int v = 0; v < 9; v++) acc[v] = fma(h, w[v], acc[v]);
        }
    }
    double* pb = pbuf + (slot * 9 + qv) * 9;
#pragma unroll
    for (int v = 0; v < 9; v++) pb[v] = acc[v];
    __builtin_amdgcn_wave_barrier();
    // C: y[v=qv] = sum over chunks (canonical q order, same as R6)
    double y = 0.0;
#pragma unroll
    for (int q2 = 0; q2 < 9; q2++) y += pbuf[(slot * 9 + q2) * 9 + qv];
    ybuf[slot * 9 + qv] = y;
    __builtin_amdgcn_wave_barrier();
    double m = ybuf[slot * 9 + 0];
#pragma unroll
    for (int v2 = 1; v2 < 9; v2++) m = fmax(m, ybuf[slot * 9 + v2]);
    double e = exp(y - m);
    __builtin_amdgcn_wave_barrier();     // all max-reads done before overwrite
    ybuf[slot * 9 + qv] = e;
    __builtin_amdgcn_wave_barrier();
    double p[9], sum = 0.0;
#pragma unroll
    for (int v2 = 0; v2 < 9; v2++) { p[v2] = ybuf[slot * 9 + v2]; sum += p[v2]; }
    double inv = 1.0 / sum;
    outp[cell * 9 + qv] = (float)(p[qv] * inv);
    if (qv == 0) {
        double best = -1.0; int bvv = 0;
#pragma unroll
        for (int v2 = 0; v2 < 9; v2++) {
            double pr = p[v2] * inv;
            if (pr > best) { best = pr; bvv = v2; }  // strict > : first-index tie-break
        }
        score_l[cell] = best;
        pos_l[cell] = bvv;
    }
}

__global__ __launch_bounds__(TPB, 3) void sudoku_kernel(
    const float* __restrict__ x_in,
    const float* __restrict__ W1,
    const float* __restrict__ W2,
    float* __restrict__ out,
    int nb)
{
    const int b = blockIdx.x;
    const int t = threadIdx.x;
    const int W = t >> 6, l = t & 63;
    const int ls = l / 9, qv = l - 9 * ls;   // local slot, chunk/value id

    __shared__ float  xs[729];
    __shared__ double W2Td[100 * 9];   // 7.2 KB
    __shared__ double cnt[27 * 9];     // 1.9 KB, exact small ints
    __shared__ double H1[27 * 101];    // 21.8 KB
    __shared__ double pbuf[24 * 81];   // 15.6 KB [slot][q][v]
    __shared__ double ybuf[24 * 9];    // 1.7 KB (holds y, then exp)
    __shared__ double score_l[81];     // -1 = filled
    __shared__ int    pos_l[81];

    float* outp = out + (size_t)b * 729;
    const float* xb = x_in + (size_t)b * 729;
    for (int i = t; i < 729; i += TPB) { float v = xb[i]; xs[i] = v; outp[i] = v; }
    for (int i = t; i < 900; i += TPB) { int v = i / 100, j = i - 100 * v; W2Td[j * 9 + v] = (double)W2[i]; }
    __syncthreads();

    // empty flags + initial counts
    if (t < 81) {
        float s = 0.f;
#pragma unroll
        for (int v = 0; v < 9; v++) s += xs[t * 9 + v];
        score_l[t] = (s == 0.f) ? 0.0 : -1.0;
        pos_l[t] = 0;
    }
    for (int o = t; o < 243; o += TPB) {
        int g = o / 9, v = o - 9 * g;
        float s = 0.f;
        if (g < 9) {
            int base = g * 9;
#pragma unroll
            for (int k = 0; k < 9; k++) s += xs[(base + k) * 9 + v];
        } else if (g < 18) {
            int c = g - 9;
#pragma unroll
            for (int k = 0; k < 9; k++) s += xs[(c + 9 * k) * 9 + v];
        } else {
            int bx = g - 18;
            int base = (bx / 3) * 27 + (bx % 3) * 3;
#pragma unroll
            for (int k = 0; k < 9; k++) s += xs[(base + (k / 3) * 9 + (k % 3)) * 9 + v];
        }
        cnt[g * 9 + v] = (double)s;
    }
    __syncthreads();

    // full H1 init (canonical v-order)
    for (int o = t; o < 2700; o += TPB) {
        int g = o / 100, j = o - 100 * g;
        int type = (g >= 18) ? 2 : (g >= 9 ? 1 : 0);
        const float* w = W1 + j * 27 + type * 9;
        const double* cc = cnt + g * 9;
        double s = 0.0;
#pragma unroll
        for (int v = 0; v < 9; v++) s = fma((double)w[v], cc[v], s);
        H1[g * 101 + j] = s;
    }
    int myflag = (t < 81) ? (score_l[t] == 0.0) : 0;
    int ne = __syncthreads_count(myflag);   // barrier: H1/flags visible

    // initial probs for all empty cells: wave-local, no inner barriers
    for (int c0 = 0; c0 < 96; c0 += 24) {
        if (l < 54) {
            int slot = W * 6 + ls;          // 0..23
            int cell = c0 + slot;
            if (cell < 81 && score_l[cell] >= 0.0)
                do_FC(slot, qv, cell, H1, W2Td, pbuf, ybuf, outp, score_l, pos_l);
        }
    }
    __syncthreads();

    // main loop: one fill per iteration, 2 barriers per step
    for (int step = 0; step < ne; ++step) {
        // ARG: every wave computes the argmax redundantly (identical result)
        double s = score_l[l]; int idx = l;
        if (l < 17) {
            double s2 = score_l[64 + l];
            if (s2 > s) { s = s2; idx = 64 + l; }   // tie keeps lower idx
        }
#pragma unroll
        for (int off = 1; off < 64; off <<= 1) {
            double s2 = __shfl_xor(s, off);
            int    i2 = __shfl_xor(idx, off);
            if (s2 > s || (s2 == s && i2 < idx)) { s = s2; idx = i2; }
        }
        const int fcell = idx;
        const int bv = pos_l[fcell];
        const int fr = fcell / 9, fcc = fcell - 9 * fr;
        const int fbx = (fr / 3) * 3 + fcc / 3;

        // H: fresh H1 for the 3 dirty groups, exact inline +1 correction
        for (int o = t; o < 300; o += TPB) {
            int gi = o / 100, j = o - 100 * gi;
            int g = (gi == 0) ? fr : (gi == 1) ? (9 + fcc) : (18 + fbx);
            const float* w = W1 + j * 27 + gi * 9;
            const double* cc = cnt + g * 9;
            double h = 0.0;
#pragma unroll
            for (int v = 0; v < 9; v++) {
                double cv = cc[v] + (v == bv ? 1.0 : 0.0);   // exact
                h = fma((double)w[v], cv, h);
            }
            H1[g * 101 + j] = h;
        }
        __syncthreads();

        // F+C (wave-local) + deferred state writes
        if (t == 0) {
            xs[fcell * 9 + bv] = 1.0f;
            score_l[fcell] = -1.0;
            cnt[fr * 9 + bv] += 1.0;
            cnt[(9 + fcc) * 9 + bv] += 1.0;
            cnt[(18 + fbx) * 9 + bv] += 1.0;
        }
        if (l < 54) {
            int slot = W * 6 + ls;
            if (slot < 22) {
                int cell = affected_cell(slot, fr, fcc);
                if (cell != fcell && score_l[cell] >= 0.0)
                    do_FC(slot, qv, cell, H1, W2Td, pbuf, ybuf, outp, score_l, pos_l);
            }
        }
        __syncthreads();
    }

    float* outx = out + (size_t)nb * 729 + (size_t)b * 729;
    for (int i = t; i < 729; i += TPB) outx[i] = xs[i];
}

extern "C" void kernel_launch(void* const* d_in, const int* in_sizes, int n_in,
                              void* d_out, int out_size, void* d_ws, size_t ws_size,
                              hipStream_t stream) {
    const float* x  = (const float*)d_in[0];
    const float* W1 = (const float*)d_in[1];
    const float* W2 = (const float*)d_in[2];
    int nb = in_sizes[0] / 729;
    (void)n_in; (void)out_size; (void)d_ws; (void)ws_size;
    sudoku_kernel<<<nb, TPB, 0, stream>>>(x, W1, W2, (float*)d_out, nb);
}